// Round 15
// baseline (512.313 us; speedup 1.0000x reference)
//
#include <hip/hip_runtime.h>
#include <stdint.h>

// KVCacheAttention: B=4, Sq=2048, Scache=6144, Skv=8192, D=1024, scale=1/8.
// Round 15: r13 quadrant-phase GEMM + staggered reads with counted lgkm,
// FIXED from r14's race: staggered reads issue POST-barrier (cross-wave LDS
// visibility = every wave's VMC4 + barrier; VMC4 alone is per-wave only).
// p0: {read A0,B0 pre-bar; SA0; VMC4; bar; read B1; lgkm(4); MFMA(0,0)}
// p1: {SB0; VMC4; bar; read A1->aG; lgkm(8); MFMA(0,1)}
// p2: {SB1; bar; lgkm(0); MFMA(1,1)}   p3: {SA1; VMC4; bar; MFMA(1,0)}
// Everything else identical to round 13 (best passing: 439 us).

#define DM 1024
#define NB 4
#define SQN 2048
#define SCC 6144
#define SKV 8192
#define NSPLIT 2
#define KSP (SKV / NSPLIT)

typedef unsigned short u16;
typedef __attribute__((ext_vector_type(8))) short short8;
typedef __attribute__((ext_vector_type(4))) float f32x4;

__device__ __forceinline__ u16 f2bf(float x) {
  unsigned u = __builtin_bit_cast(unsigned, x);
  u += 0x7fffu + ((u >> 16) & 1u);  // RNE; inputs finite
  return (u16)(u >> 16);
}

__device__ __forceinline__ void gll16(const void* g, void* l) {
  __builtin_amdgcn_global_load_lds(
      (const __attribute__((address_space(1))) void*)g,
      (__attribute__((address_space(3))) void*)l, 16, 0, 0);
}

#define FENCE() asm volatile("" ::: "memory")
#define BARRIER()                      \
  do {                                 \
    FENCE();                           \
    __builtin_amdgcn_s_barrier();      \
    FENCE();                           \
  } while (0)

#define DSR(d, a, I) \
  asm volatile("ds_read_b128 %0, %1 offset:%2" : "=v"(d) : "v"(a), "i"(I))

#define VMC4() asm volatile("s_waitcnt vmcnt(4)" ::: "memory")
#define LGKMN(N)                                            \
  do {                                                      \
    asm volatile("s_waitcnt lgkmcnt(" #N ")" ::: "memory"); \
    __builtin_amdgcn_sched_barrier(0);                      \
  } while (0)

// ---------------- conversions ----------------
__global__ __launch_bounds__(256) void k_cvt(const float* __restrict__ in,
                                             u16* __restrict__ out, long n4) {
  long i = (long)blockIdx.x * 256 + threadIdx.x;
  long st = (long)gridDim.x * 256;
  for (; i < n4; i += st) {
    float4 v = ((const float4*)in)[i];
    ushort4 u;
    u.x = f2bf(v.x); u.y = f2bf(v.y); u.z = f2bf(v.z); u.w = f2bf(v.w);
    ((ushort4*)out)[i] = u;
  }
}

// cached_key [4][6144][1024] f32 -> K bf16 [4][8192][1024] rows 0..6143
__global__ __launch_bounds__(256) void k_cvt_ck(const float* __restrict__ in,
                                                u16* __restrict__ out) {
  const long n4 = (long)NB * SCC * DM / 4;
  long i = (long)blockIdx.x * 256 + threadIdx.x;
  long st = (long)gridDim.x * 256;
  for (; i < n4; i += st) {
    float4 v = ((const float4*)in)[i];
    ushort4 u;
    u.x = f2bf(v.x); u.y = f2bf(v.y); u.z = f2bf(v.z); u.w = f2bf(v.w);
    long e = i * 4;
    int b = (int)(e / ((long)SCC * DM));
    long rem = e - (long)b * SCC * DM;
    *(ushort4*)(out + (long)b * SKV * DM + rem) = u;
  }
}

// ---------------- V^T builder ----------------
__global__ __launch_bounds__(256) void k_build_vt(const float* __restrict__ cv,
                                                  const u16* __restrict__ vtmp,
                                                  u16* __restrict__ VT) {
  __shared__ u16 t[64][65];
  const int kv0 = blockIdx.x * 64;
  const int d0 = blockIdx.y * 64;
  const int b = blockIdx.z;
  const int c = threadIdx.x & 63;
  const int r4 = threadIdx.x >> 6;
#pragma unroll
  for (int p = 0; p < 16; ++p) {
    int kr = p * 4 + r4;
    int kv = kv0 + kr;
    int d = d0 + c;
    u16 u;
    if (kv < SCC)
      u = f2bf(cv[((long)b * SCC + kv) * DM + d]);
    else
      u = vtmp[((long)b * SQN + (kv - SCC)) * DM + d];
    t[kr][c] = u;
  }
  __syncthreads();
#pragma unroll
  for (int p = 0; p < 16; ++p) {
    int dr = p * 4 + r4;
    VT[((long)b * DM + d0 + dr) * SKV + kv0 + c] = t[c][dr];
  }
}

// ---------------- 256x256xBK64 quadrant-phase NT GEMM ----------------
// 512 thr = 8 waves (2M x 4N); per-wave out 128x64.
// LDS 128 KiB: A[2buf][2half][128r][64k] @0, B same @65536.
// 16B slot ^= row&7 via pre-swizzled source; linear gll16 dests.
template <int MODE>
__global__ __launch_bounds__(512, 2) void k_gemm8(
    const u16* __restrict__ A, const u16* __restrict__ B0,
    void* __restrict__ C0, void* __restrict__ C1, void* __restrict__ C2,
    float* __restrict__ sums, const float* __restrict__ bias0,
    const float* __restrict__ bias1, const float* __restrict__ bias2) {
  extern __shared__ char smem[];
  const int tid = threadIdx.x;
  const int lane = tid & 63;
  const int wv = tid >> 6;   // 0..7
  const int wr = wv >> 2;    // 0..1
  const int wc = wv & 3;     // 0..3
  const int bm = blockIdx.y * 256;  // A rows
  const int bn = blockIdx.x * 256;  // B rows
  const int z = blockIdx.z;

  constexpr int LD = (MODE == 2) ? SKV : DM;
  constexpr int NT = ((MODE == 2) ? KSP : DM) / 64;

  const u16 *Ab_, *Bb_;
  if constexpr (MODE == 0) {
    Ab_ = A + (long)bm * LD;          // W-stack rows: out-d
    Bb_ = B0 + (long)bn * LD;         // H tokens
  } else if constexpr (MODE == 1) {
    Ab_ = A + ((long)z * SKV + bm) * LD;   // K rows: kv
    Bb_ = B0 + ((long)z * SQN + bn) * LD;  // Q rows: q
  } else {
    const int bb_ = z / NSPLIT, sp = z % NSPLIT;
    Ab_ = A + ((long)bb_ * SQN + bm) * (long)SKV + (long)sp * KSP;
    Bb_ = B0 + ((long)bb_ * DM + bn) * (long)SKV + (long)sp * KSP;
  }

  // ---- staging addresses (per-lane global, linear LDS dest) ----
  const int sg = tid >> 3;                     // 0..63
  const int ssl = ((tid & 7) ^ (sg & 7)) * 8;  // pre-swizzled col (elems)
  const u16* gA[2][2];  // [mh][g]: grow = g*128 + mh*64 + sg
  const u16* gB[2][2];  // [nh][g]: grow = (g*2 + (sg>>5))*64 + nh*32 + (sg&31)
#pragma unroll
  for (int mh = 0; mh < 2; ++mh)
#pragma unroll
    for (int g = 0; g < 2; ++g) {
      gA[mh][g] = Ab_ + (long)(g * 128 + mh * 64 + sg) * LD + ssl;
      gB[mh][g] = Bb_ + (long)((g * 2 + (sg >> 5)) * 64 + mh * 32 + (sg & 31)) * LD + ssl;
    }
  u16* lA = (u16*)smem + tid * 8;           // + bufN*16384 + mh*8192 + g*4096
  u16* lB = (u16*)smem + 32768 + tid * 8;

#define SA(MH, BUFN, KO)                                              \
  do {                                                                \
    gll16(gA[MH][0] + (KO), lA + (BUFN)*16384 + (MH)*8192);           \
    gll16(gA[MH][1] + (KO), lA + (BUFN)*16384 + (MH)*8192 + 4096);    \
  } while (0)
#define SB(NH, BUFN, KO)                                              \
  do {                                                                \
    gll16(gB[NH][0] + (KO), lB + (BUFN)*16384 + (NH)*8192);           \
    gll16(gB[NH][1] + (KO), lB + (BUFN)*16384 + (NH)*8192 + 4096);    \
  } while (0)

  // prologue: stage tile 0 halves A0,B0,B1,A1; VMC4 -> A0,B0 certified
  SA(0, 0, 0);
  SB(0, 0, 0);
  SB(1, 0, 0);
  SA(1, 0, 0);
  VMC4();
  BARRIER();

  f32x4 acc[8][4];
#pragma unroll
  for (int m = 0; m < 8; ++m)
#pragma unroll
    for (int n = 0; n < 4; ++n)
#pragma unroll
      for (int j = 0; j < 4; ++j) acc[m][n][j] = 0.0f;

  const int alane = lane & 15;
  const int sw = lane & 7;
  const int s0 = lane >> 4;
  const int slot0 = ((s0 ^ sw) * 16);
  const int slot1 = (((s0 + 4) ^ sw) * 16);
  const int aBase = (wr * 64 + alane) * 128;  // + imm mh*16384 + ms*2048
  const int bBase = (wc * 32 + alane) * 128;  // + imm nh*16384 + ns*2048

  short8 aF[4][2];     // A-half mh0 frags [ms][kk]
  short8 aG[4][2];     // A-half mh1 frags [ms][kk]
  short8 bF[2][2][2];  // [nh][ns][kk], both halves live

#define ARD8(DST, MH, AR0, AR1)                      \
  _Pragma("unroll") for (int ms = 0; ms < 4; ++ms) { \
    DSR(DST[ms][0], AR0, (MH)*16384 + ms * 2048);    \
    DSR(DST[ms][1], AR1, (MH)*16384 + ms * 2048);    \
  }
#define BRD4(NH, BR0, BR1)                          \
  _Pragma("unroll") for (int ns = 0; ns < 2; ++ns) { \
    DSR(bF[NH][ns][0], BR0, (NH)*16384 + ns * 2048); \
    DSR(bF[NH][ns][1], BR1, (NH)*16384 + ns * 2048); \
  }
#define MFMA_Q(AFR, MH, NH)                                                \
  do {                                                                     \
    __builtin_amdgcn_s_setprio(1);                                         \
    _Pragma("unroll") for (int ms = 0; ms < 4; ++ms)                       \
    _Pragma("unroll") for (int ns = 0; ns < 2; ++ns)                       \
    _Pragma("unroll") for (int kk = 0; kk < 2; ++kk)                       \
        acc[(MH)*4 + ms][(NH)*2 + ns] =                                    \
            __builtin_amdgcn_mfma_f32_16x16x32_bf16(                       \
                AFR[ms][kk], bF[NH][ns][kk], acc[(MH)*4 + ms][(NH)*2 + ns],\
                0, 0, 0);                                                  \
    __builtin_amdgcn_s_setprio(0);                                         \
    __builtin_amdgcn_sched_barrier(0);                                     \
  } while (0)

// One K-tile: 4 quadrant phases, staggered POST-BARRIER reads + counted lgkm.
// Cross-wave certification (VMC4-then-barrier, never VMC4 alone):
//   SB1(t) drained by every wave's p0(t) VMC4 -> p0 barrier -> B1 read safe.
//   SA1(t) drained by every wave's p1(t) VMC4 -> p1 barrier -> A1 read safe.
//   SA0/SB0(t+1) drained by p3(t) VMC4 -> p3 barrier -> p0(t+1) reads safe.
#define TILE_BODY(BUF, KT)                                            \
  do {                                                                \
    const long ko = (long)(((KT) + 1 < NT) ? (KT) + 1 : (KT)) * 64;   \
    const int aR0 = (BUF)*32768 + aBase + slot0;                      \
    const int aR1 = (BUF)*32768 + aBase + slot1;                      \
    const int bR0 = 65536 + (BUF)*32768 + bBase + slot0;              \
    const int bR1 = 65536 + (BUF)*32768 + bBase + slot1;              \
    /* p0: Q(mh0,nh0) */                                              \
    ARD8(aF, 0, aR0, aR1);                                            \
    BRD4(0, bR0, bR1);                                                \
    SA(0, (BUF) ^ 1, ko);                                             \
    VMC4();                                                           \
    BARRIER();                                                        \
    BRD4(1, bR0, bR1);                                                \
    LGKMN(4);                                                         \
    MFMA_Q(aF, 0, 0);                                                 \
    /* p1: Q(mh0,nh1) */                                              \
    SB(0, (BUF) ^ 1, ko);                                             \
    VMC4();                                                           \
    BARRIER();                                                        \
    ARD8(aG, 1, aR0, aR1);                                            \
    LGKMN(8);                                                         \
    MFMA_Q(aF, 0, 1);                                                 \
    /* p2: Q(mh1,nh1) */                                              \
    SB(1, (BUF) ^ 1, ko);                                             \
    BARRIER();                                                        \
    LGKMN(0);                                                         \
    MFMA_Q(aG, 1, 1);                                                 \
    /* p3: Q(mh1,nh0); frags held */                                  \
    SA(1, (BUF) ^ 1, ko);                                             \
    VMC4();                                                           \
    BARRIER();                                                        \
    MFMA_Q(aG, 1, 0);                                                 \
  } while (0)

  for (int t2 = 0; t2 < NT; t2 += 2) {
    TILE_BODY(0, t2);
    TILE_BODY(1, t2 + 1);
  }
#undef TILE_BODY
#undef ARD8
#undef BRD4
#undef MFMA_Q
#undef SA
#undef SB

  // ---------------- epilogue (r13 verbatim) ----------------
  const int rsub = (lane >> 4) * 4;

  if constexpr (MODE == 0) {
    // A=W-stack: acc row = out-d, col = token. which = bm>>10 per block.
    const int which = bm >> 10;
    const float* bp = which == 0 ? bias0 : (which == 1 ? bias1 : bias2);
    u16* Cq = (u16*)C0;
    u16* Ck = (u16*)C1;
    u16* Cv = (u16*)C2;
    const int od_base = (bm & 1023) + wr * 128 + rsub;
#pragma unroll
    for (int n = 0; n < 4; ++n) {
      int token = bn + wc * 64 + n * 16 + alane;
      u16* dst;
      if (which == 1) {
        int b = token >> 11, ss = token & 2047;
        dst = Ck + ((long)b * SKV + SCC + ss) * DM;
      } else if (which == 0) {
        dst = Cq + (long)token * DM;
      } else {
        dst = Cv + (long)token * DM;
      }
#pragma unroll
      for (int m = 0; m < 8; ++m) {
        int cc = od_base + m * 16;
        float4 bb = *(const float4*)(bp + cc);
        ushort4 u;
        u.x = f2bf(acc[m][n][0] + bb.x);
        u.y = f2bf(acc[m][n][1] + bb.y);
        u.z = f2bf(acc[m][n][2] + bb.z);
        u.w = f2bf(acc[m][n][3] + bb.w);
        *(ushort4*)(dst + cc) = u;
      }
    }
  } else if constexpr (MODE == 1) {
    // A=K: acc row = kv, col = q. store P[q][kv] ushort4; rowsum per q.
    u16* Pp = (u16*)C0 + (long)z * SQN * SKV;
    float* sb = sums + z * SQN;
    const float CE = 0.18033688011112042f;  // log2(e)/8
    const int kv_base = bm + wr * 128 + rsub;
#pragma unroll
    for (int n = 0; n < 4; ++n) {
      int q = bn + wc * 64 + n * 16 + alane;
      u16* prow = Pp + (long)q * SKV;
      float part = 0.f;
#pragma unroll
      for (int m = 0; m < 8; ++m) {
        int kv = kv_base + m * 16;
        float e0 = exp2f(acc[m][n][0] * CE);
        float e1 = exp2f(acc[m][n][1] * CE);
        float e2 = exp2f(acc[m][n][2] * CE);
        float e3 = exp2f(acc[m][n][3] * CE);
        part += (e0 + e1) + (e2 + e3);
        ushort4 u;
        u.x = f2bf(e0); u.y = f2bf(e1); u.z = f2bf(e2); u.w = f2bf(e3);
        *(ushort4*)(prow + kv) = u;
      }
      part += __shfl_xor(part, 16);
      part += __shfl_xor(part, 32);
      if ((lane >> 4) == 0) atomicAdd(&sb[q], part);
    }
  } else {
    // acc row = q, col = d. f32 stores, 64B sectors.
    float* Cp = (float*)C0 + (long)z * SQN * DM;
#pragma unroll
    for (int n = 0; n < 4; ++n) {
      int col = bn + wc * 64 + n * 16 + alane;
#pragma unroll
      for (int m = 0; m < 8; ++m)
#pragma unroll
        for (int j = 0; j < 4; ++j) {
          int row = bm + wr * 128 + m * 16 + rsub + j;
          Cp[(long)row * DM + col] = acc[m][n][j];
        }
    }
  }
}

// ---------------- reduce split-K partials + normalize ----------------
__global__ __launch_bounds__(256) void k_reduce(const float* __restrict__ Op,
                                                const float* __restrict__ sums,
                                                float* __restrict__ out) {
  const long n4 = (long)NB * SQN * DM / 4;
  long i = (long)blockIdx.x * 256 + threadIdx.x;
  if (i >= n4) return;
  long e = i * 4;
  int b = (int)(e / ((long)SQN * DM));
  long rem = e - (long)b * SQN * DM;
  int row = (int)(rem / DM);
  const long z4 = (long)SQN * DM / 4;
  long i0 = (long)(b * NSPLIT) * z4 + (rem >> 2);
  float4 a0 = ((const float4*)Op)[i0];
  float4 a1 = ((const float4*)Op)[i0 + z4];
  float inv = 1.0f / sums[b * SQN + row];
  float4 r;
  r.x = (a0.x + a1.x) * inv;
  r.y = (a0.y + a1.y) * inv;
  r.z = (a0.z + a1.z) * inv;
  r.w = (a0.w + a1.w) * inv;
  ((float4*)out)[i] = r;
}

// ---------------- launch ----------------
extern "C" void kernel_launch(void* const* d_in, const int* in_sizes, int n_in,
                              void* d_out, int out_size, void* d_ws, size_t ws_size,
                              hipStream_t stream) {
  const float* hidden = (const float*)d_in[0];
  const float* ck = (const float*)d_in[1];
  const float* cv = (const float*)d_in[2];
  const float* Wq = (const float*)d_in[3];
  const float* bq = (const float*)d_in[4];
  const float* Wk = (const float*)d_in[5];
  const float* bk = (const float*)d_in[6];
  const float* Wv = (const float*)d_in[7];
  const float* bv = (const float*)d_in[8];
  (void)in_sizes; (void)n_in; (void)out_size; (void)ws_size;

  hipFuncSetAttribute(reinterpret_cast<const void*>(&k_gemm8<0>),
                      hipFuncAttributeMaxDynamicSharedMemorySize, 131072);
  hipFuncSetAttribute(reinterpret_cast<const void*>(&k_gemm8<1>),
                      hipFuncAttributeMaxDynamicSharedMemorySize, 131072);
  hipFuncSetAttribute(reinterpret_cast<const void*>(&k_gemm8<2>),
                      hipFuncAttributeMaxDynamicSharedMemorySize, 131072);

  char* base = (char*)d_ws;
  size_t off = 0;
  auto alloc = [&](size_t bytes) {
    char* p = base + off;
    off = (off + bytes + 255) & ~(size_t)255;
    return p;
  };
  // region0 (dead before PV): Hb, weights, Qb, Kb, Vtmp. Opart aliases it.
  u16* Hb = (u16*)alloc((size_t)NB * SQN * DM * 2);
  u16* Wall = (u16*)alloc((size_t)3 * DM * DM * 2);  // Wq|Wk|Wv stacked
  u16* Qb = (u16*)alloc((size_t)NB * SQN * DM * 2);
  u16* Kb = (u16*)alloc((size_t)NB * SKV * DM * 2);
  u16* Vtmp = (u16*)alloc((size_t)NB * SQN * DM * 2);
  float* Opart = (float*)base;  // [NB*NSPLIT][2048][1024] f32, aliases region0
  size_t opart_bytes = (size_t)NB * NSPLIT * SQN * DM * 4;
  if (off < opart_bytes) off = (opart_bytes + 255) & ~(size_t)255;
  u16* VT = (u16*)alloc((size_t)NB * DM * SKV * 2);
  u16* P = (u16*)alloc((size_t)NB * SQN * SKV * 2);
  float* sums = (float*)alloc((size_t)NB * SQN * 4);

  // conversions
  k_cvt<<<2048, 256, 0, stream>>>(hidden, Hb, (long)NB * SQN * DM / 4);
  k_cvt<<<512, 256, 0, stream>>>(Wq, Wall, (long)DM * DM / 4);
  k_cvt<<<512, 256, 0, stream>>>(Wk, Wall + (size_t)DM * DM, (long)DM * DM / 4);
  k_cvt<<<512, 256, 0, stream>>>(Wv, Wall + (size_t)2 * DM * DM, (long)DM * DM / 4);
  k_cvt_ck<<<4096, 256, 0, stream>>>(ck, Kb);

  // fused QKV projection: A=W-stack [3072][1024], B=H [8192][1024]
  k_gemm8<0><<<dim3(32, 12, 1), 512, 131072, stream>>>(
      Wall, Hb, Qb, Kb, Vtmp, nullptr, bq, bk, bv);

  // V^T
  k_build_vt<<<dim3(SKV / 64, DM / 64, NB), 256, 0, stream>>>(cv, Vtmp, VT);

  // S^T = K.Q^T with fused exp + row sums (batched over 4): A=K, B=Q
  hipMemsetAsync(sums, 0, (size_t)NB * SQN * 4, stream);
  k_gemm8<1><<<dim3(SQN / 256, SKV / 256, NB), 512, 131072, stream>>>(
      Kb, Qb, P, nullptr, nullptr, sums, nullptr, nullptr, nullptr);

  // PV split-K(2): A=P, B=VT
  k_gemm8<2><<<dim3(DM / 256, SQN / 256, NB * NSPLIT), 512, 131072, stream>>>(
      P, VT, Opart, nullptr, nullptr, nullptr, nullptr, nullptr, nullptr);

  // reduce partials + normalize
  k_reduce<<<(NB * SQN * DM / 4 + 255) / 256, 256, 0, stream>>>(
      Opart, sums, (float*)d_out);
}

// Round 16
// 427.977 us; speedup vs baseline: 1.1971x; 1.1971x over previous
//
#include <hip/hip_runtime.h>
#include <stdint.h>

// KVCacheAttention: B=4, Sq=2048, Scache=6144, Skv=8192, D=1024, scale=1/8.
// Round 16: round-13 kernels VERBATIM (best passing: 439 us; quadrant-phase
// 256x256xBK64 GEMM, pre-barrier reads, lgkm0, VMC4@p0/p1/p3) + all prep
// (hidden/W/ck f32->bf16 conversions + sums zeroing) fused into ONE
// grid-stride kernel: 11 dispatches -> 7 (launch-gap + tail savings).

#define DM 1024
#define NB 4
#define SQN 2048
#define SCC 6144
#define SKV 8192
#define NSPLIT 2
#define KSP (SKV / NSPLIT)

typedef unsigned short u16;
typedef __attribute__((ext_vector_type(8))) short short8;
typedef __attribute__((ext_vector_type(4))) float f32x4;

__device__ __forceinline__ u16 f2bf(float x) {
  unsigned u = __builtin_bit_cast(unsigned, x);
  u += 0x7fffu + ((u >> 16) & 1u);  // RNE; inputs finite
  return (u16)(u >> 16);
}

__device__ __forceinline__ ushort4 cv4(float4 v) {
  ushort4 u;
  u.x = f2bf(v.x); u.y = f2bf(v.y); u.z = f2bf(v.z); u.w = f2bf(v.w);
  return u;
}

__device__ __forceinline__ void gll16(const void* g, void* l) {
  __builtin_amdgcn_global_load_lds(
      (const __attribute__((address_space(1))) void*)g,
      (__attribute__((address_space(3))) void*)l, 16, 0, 0);
}

#define FENCE() asm volatile("" ::: "memory")
#define BARRIER()                      \
  do {                                 \
    FENCE();                           \
    __builtin_amdgcn_s_barrier();      \
    FENCE();                           \
  } while (0)

#define DSR(d, a, I) \
  asm volatile("ds_read_b128 %0, %1 offset:%2" : "=v"(d) : "v"(a), "i"(I))

#define VMC4() asm volatile("s_waitcnt vmcnt(4)" ::: "memory")
#define LGKM0()                                        \
  do {                                                 \
    asm volatile("s_waitcnt lgkmcnt(0)" ::: "memory"); \
    __builtin_amdgcn_sched_barrier(0);                 \
  } while (0)

// ---------------- fused prep: conversions + sums zero ----------------
// ranges (float4 units): [0,NH) hidden->Hb; [NH,T1) Wq|Wk|Wv->Wall;
// [T1,T2) ck->Kb (row remap); [T2,T3) zero sums.
__global__ __launch_bounds__(256) void k_prep(
    const float* __restrict__ hidden, const float* __restrict__ Wq,
    const float* __restrict__ Wk, const float* __restrict__ Wv,
    const float* __restrict__ ck, u16* __restrict__ Hb,
    u16* __restrict__ Wall, u16* __restrict__ Kb, float* __restrict__ sums) {
  const long NH = (long)NB * SQN * DM / 4;
  const long NW = (long)DM * DM / 4;
  const long NC = (long)NB * SCC * DM / 4;
  const long T1 = NH + 3 * NW;
  const long T2 = T1 + NC;
  const long T3 = T2 + (long)NB * SQN / 4;
  long i = (long)blockIdx.x * 256 + threadIdx.x;
  const long st = (long)gridDim.x * 256;
  for (; i < T3; i += st) {
    if (i < NH) {
      ((ushort4*)Hb)[i] = cv4(((const float4*)hidden)[i]);
    } else if (i < T1) {
      long r = i - NH;
      int w = (int)(r / NW);
      long o = r - (long)w * NW;
      const float* src = w == 0 ? Wq : (w == 1 ? Wk : Wv);
      ((ushort4*)Wall)[r] = cv4(((const float4*)src)[o]);
    } else if (i < T2) {
      long r = i - T1;
      float4 v = ((const float4*)ck)[r];
      long e = r * 4;
      int b = (int)(e / ((long)SCC * DM));
      long rem = e - (long)b * SCC * DM;
      *(ushort4*)(Kb + (long)b * SKV * DM + rem) = cv4(v);
    } else {
      float4 z;
      z.x = 0.f; z.y = 0.f; z.z = 0.f; z.w = 0.f;
      ((float4*)sums)[i - T2] = z;
    }
  }
}

// ---------------- V^T builder ----------------
__global__ __launch_bounds__(256) void k_build_vt(const float* __restrict__ cv,
                                                  const u16* __restrict__ vtmp,
                                                  u16* __restrict__ VT) {
  __shared__ u16 t[64][65];
  const int kv0 = blockIdx.x * 64;
  const int d0 = blockIdx.y * 64;
  const int b = blockIdx.z;
  const int c = threadIdx.x & 63;
  const int r4 = threadIdx.x >> 6;
#pragma unroll
  for (int p = 0; p < 16; ++p) {
    int kr = p * 4 + r4;
    int kv = kv0 + kr;
    int d = d0 + c;
    u16 u;
    if (kv < SCC)
      u = f2bf(cv[((long)b * SCC + kv) * DM + d]);
    else
      u = vtmp[((long)b * SQN + (kv - SCC)) * DM + d];
    t[kr][c] = u;
  }
  __syncthreads();
#pragma unroll
  for (int p = 0; p < 16; ++p) {
    int dr = p * 4 + r4;
    VT[((long)b * DM + d0 + dr) * SKV + kv0 + c] = t[c][dr];
  }
}

// ---------------- 256x256xBK64 quadrant-phase NT GEMM (r13) ----------------
// 512 thr = 8 waves (2M x 4N); per-wave out 128x64.
// LDS 128 KiB: A[2buf][2half][128r][64k] @0, B same @65536.
// 16B slot ^= row&7 via pre-swizzled source; linear gll16 dests.
template <int MODE>
__global__ __launch_bounds__(512, 2) void k_gemm8(
    const u16* __restrict__ A, const u16* __restrict__ B0,
    void* __restrict__ C0, void* __restrict__ C1, void* __restrict__ C2,
    float* __restrict__ sums, const float* __restrict__ bias0,
    const float* __restrict__ bias1, const float* __restrict__ bias2) {
  extern __shared__ char smem[];
  const int tid = threadIdx.x;
  const int lane = tid & 63;
  const int wv = tid >> 6;   // 0..7
  const int wr = wv >> 2;    // 0..1
  const int wc = wv & 3;     // 0..3
  const int bm = blockIdx.y * 256;  // A rows
  const int bn = blockIdx.x * 256;  // B rows
  const int z = blockIdx.z;

  constexpr int LD = (MODE == 2) ? SKV : DM;
  constexpr int NT = ((MODE == 2) ? KSP : DM) / 64;

  const u16 *Ab_, *Bb_;
  if constexpr (MODE == 0) {
    Ab_ = A + (long)bm * LD;          // W-stack rows: out-d
    Bb_ = B0 + (long)bn * LD;         // H tokens
  } else if constexpr (MODE == 1) {
    Ab_ = A + ((long)z * SKV + bm) * LD;   // K rows: kv
    Bb_ = B0 + ((long)z * SQN + bn) * LD;  // Q rows: q
  } else {
    const int bb_ = z / NSPLIT, sp = z % NSPLIT;
    Ab_ = A + ((long)bb_ * SQN + bm) * (long)SKV + (long)sp * KSP;
    Bb_ = B0 + ((long)bb_ * DM + bn) * (long)SKV + (long)sp * KSP;
  }

  // ---- staging addresses (per-lane global, linear LDS dest) ----
  const int sg = tid >> 3;                     // 0..63
  const int ssl = ((tid & 7) ^ (sg & 7)) * 8;  // pre-swizzled col (elems)
  const u16* gA[2][2];  // [mh][g]: grow = g*128 + mh*64 + sg
  const u16* gB[2][2];  // [nh][g]: grow = (g*2 + (sg>>5))*64 + nh*32 + (sg&31)
#pragma unroll
  for (int mh = 0; mh < 2; ++mh)
#pragma unroll
    for (int g = 0; g < 2; ++g) {
      gA[mh][g] = Ab_ + (long)(g * 128 + mh * 64 + sg) * LD + ssl;
      gB[mh][g] = Bb_ + (long)((g * 2 + (sg >> 5)) * 64 + mh * 32 + (sg & 31)) * LD + ssl;
    }
  u16* lA = (u16*)smem + tid * 8;           // + bufN*16384 + mh*8192 + g*4096
  u16* lB = (u16*)smem + 32768 + tid * 8;

#define SA(MH, BUFN, KO)                                              \
  do {                                                                \
    gll16(gA[MH][0] + (KO), lA + (BUFN)*16384 + (MH)*8192);           \
    gll16(gA[MH][1] + (KO), lA + (BUFN)*16384 + (MH)*8192 + 4096);    \
  } while (0)
#define SB(NH, BUFN, KO)                                              \
  do {                                                                \
    gll16(gB[NH][0] + (KO), lB + (BUFN)*16384 + (NH)*8192);           \
    gll16(gB[NH][1] + (KO), lB + (BUFN)*16384 + (NH)*8192 + 4096);    \
  } while (0)

  // prologue: stage tile 0 halves A0,B0,B1,A1; VMC4 -> A0,B0 certified
  SA(0, 0, 0);
  SB(0, 0, 0);
  SB(1, 0, 0);
  SA(1, 0, 0);
  VMC4();
  BARRIER();

  f32x4 acc[8][4];
#pragma unroll
  for (int m = 0; m < 8; ++m)
#pragma unroll
    for (int n = 0; n < 4; ++n)
#pragma unroll
      for (int j = 0; j < 4; ++j) acc[m][n][j] = 0.0f;

  const int alane = lane & 15;
  const int sw = lane & 7;
  const int s0 = lane >> 4;
  const int slot0 = ((s0 ^ sw) * 16);
  const int slot1 = (((s0 + 4) ^ sw) * 16);
  const int aBase = (wr * 64 + alane) * 128;  // + imm mh*16384 + ms*2048
  const int bBase = (wc * 32 + alane) * 128;  // + imm nh*16384 + ns*2048

  short8 aF[4][2];     // [ms][kk], current mh
  short8 bF[2][2][2];  // [nh][ns][kk], both halves live

#define ARD8(MH, AR0, AR1)                           \
  _Pragma("unroll") for (int ms = 0; ms < 4; ++ms) { \
    DSR(aF[ms][0], AR0, (MH)*16384 + ms * 2048);     \
    DSR(aF[ms][1], AR1, (MH)*16384 + ms * 2048);     \
  }
#define BRD4(NH, BR0, BR1)                           \
  _Pragma("unroll") for (int ns = 0; ns < 2; ++ns) { \
    DSR(bF[NH][ns][0], BR0, (NH)*16384 + ns * 2048); \
    DSR(bF[NH][ns][1], BR1, (NH)*16384 + ns * 2048); \
  }
#define MFMA_Q(MH, NH)                                                     \
  do {                                                                     \
    __builtin_amdgcn_s_setprio(1);                                         \
    _Pragma("unroll") for (int ms = 0; ms < 4; ++ms)                       \
    _Pragma("unroll") for (int ns = 0; ns < 2; ++ns)                       \
    _Pragma("unroll") for (int kk = 0; kk < 2; ++kk)                       \
        acc[(MH)*4 + ms][(NH)*2 + ns] =                                    \
            __builtin_amdgcn_mfma_f32_16x16x32_bf16(                       \
                aF[ms][kk], bF[NH][ns][kk], acc[(MH)*4 + ms][(NH)*2 + ns], \
                0, 0, 0);                                                  \
    __builtin_amdgcn_s_setprio(0);                                         \
    __builtin_amdgcn_sched_barrier(0);                                     \
  } while (0)

// One K-tile: 4 quadrant phases, all reads pre-barrier, lgkm(0) post-barrier.
#define TILE_BODY(BUF, KT)                                            \
  do {                                                                \
    const long ko = (long)(((KT) + 1 < NT) ? (KT) + 1 : (KT)) * 64;   \
    const int aR0 = (BUF)*32768 + aBase + slot0;                      \
    const int aR1 = (BUF)*32768 + aBase + slot1;                      \
    const int bR0 = 65536 + (BUF)*32768 + bBase + slot0;              \
    const int bR1 = 65536 + (BUF)*32768 + bBase + slot1;              \
    /* p0: Q(mh0,nh0) */                                              \
    ARD8(0, aR0, aR1);                                                \
    BRD4(0, bR0, bR1);                                                \
    SA(0, (BUF) ^ 1, ko);                                             \
    VMC4();                                                           \
    BARRIER();                                                        \
    LGKM0();                                                          \
    MFMA_Q(0, 0);                                                     \
    /* p1: Q(mh0,nh1) */                                              \
    BRD4(1, bR0, bR1);                                                \
    SB(0, (BUF) ^ 1, ko);                                             \
    VMC4();                                                           \
    BARRIER();                                                        \
    LGKM0();                                                          \
    MFMA_Q(0, 1);                                                     \
    /* p2: Q(mh1,nh1) */                                              \
    ARD8(1, aR0, aR1);                                                \
    SB(1, (BUF) ^ 1, ko);                                             \
    BARRIER();                                                        \
    LGKM0();                                                          \
    MFMA_Q(1, 1);                                                     \
    /* p3: Q(mh1,nh0) (all frags held) */                             \
    SA(1, (BUF) ^ 1, ko);                                             \
    VMC4();                                                           \
    BARRIER();                                                        \
    MFMA_Q(1, 0);                                                     \
  } while (0)

  for (int t2 = 0; t2 < NT; t2 += 2) {
    TILE_BODY(0, t2);
    TILE_BODY(1, t2 + 1);
  }
#undef TILE_BODY
#undef ARD8
#undef BRD4
#undef MFMA_Q
#undef SA
#undef SB

  // ---------------- epilogue (r13 verbatim) ----------------
  const int rsub = (lane >> 4) * 4;

  if constexpr (MODE == 0) {
    // A=W-stack: acc row = out-d, col = token. which = bm>>10 per block.
    const int which = bm >> 10;
    const float* bp = which == 0 ? bias0 : (which == 1 ? bias1 : bias2);
    u16* Cq = (u16*)C0;
    u16* Ck = (u16*)C1;
    u16* Cv = (u16*)C2;
    const int od_base = (bm & 1023) + wr * 128 + rsub;
#pragma unroll
    for (int n = 0; n < 4; ++n) {
      int token = bn + wc * 64 + n * 16 + alane;
      u16* dst;
      if (which == 1) {
        int b = token >> 11, ss = token & 2047;
        dst = Ck + ((long)b * SKV + SCC + ss) * DM;
      } else if (which == 0) {
        dst = Cq + (long)token * DM;
      } else {
        dst = Cv + (long)token * DM;
      }
#pragma unroll
      for (int m = 0; m < 8; ++m) {
        int cc = od_base + m * 16;
        float4 bb = *(const float4*)(bp + cc);
        ushort4 u;
        u.x = f2bf(acc[m][n][0] + bb.x);
        u.y = f2bf(acc[m][n][1] + bb.y);
        u.z = f2bf(acc[m][n][2] + bb.z);
        u.w = f2bf(acc[m][n][3] + bb.w);
        *(ushort4*)(dst + cc) = u;
      }
    }
  } else if constexpr (MODE == 1) {
    // A=K: acc row = kv, col = q. store P[q][kv] ushort4; rowsum per q.
    u16* Pp = (u16*)C0 + (long)z * SQN * SKV;
    float* sb = sums + z * SQN;
    const float CE = 0.18033688011112042f;  // log2(e)/8
    const int kv_base = bm + wr * 128 + rsub;
#pragma unroll
    for (int n = 0; n < 4; ++n) {
      int q = bn + wc * 64 + n * 16 + alane;
      u16* prow = Pp + (long)q * SKV;
      float part = 0.f;
#pragma unroll
      for (int m = 0; m < 8; ++m) {
        int kv = kv_base + m * 16;
        float e0 = exp2f(acc[m][n][0] * CE);
        float e1 = exp2f(acc[m][n][1] * CE);
        float e2 = exp2f(acc[m][n][2] * CE);
        float e3 = exp2f(acc[m][n][3] * CE);
        part += (e0 + e1) + (e2 + e3);
        ushort4 u;
        u.x = f2bf(e0); u.y = f2bf(e1); u.z = f2bf(e2); u.w = f2bf(e3);
        *(ushort4*)(prow + kv) = u;
      }
      part += __shfl_xor(part, 16);
      part += __shfl_xor(part, 32);
      if ((lane >> 4) == 0) atomicAdd(&sb[q], part);
    }
  } else {
    // acc row = q, col = d. f32 stores, 64B sectors.
    float* Cp = (float*)C0 + (long)z * SQN * DM;
#pragma unroll
    for (int n = 0; n < 4; ++n) {
      int col = bn + wc * 64 + n * 16 + alane;
#pragma unroll
      for (int m = 0; m < 8; ++m)
#pragma unroll
        for (int j = 0; j < 4; ++j) {
          int row = bm + wr * 128 + m * 16 + rsub + j;
          Cp[(long)row * DM + col] = acc[m][n][j];
        }
    }
  }
}

// ---------------- reduce split-K partials + normalize ----------------
__global__ __launch_bounds__(256) void k_reduce(const float* __restrict__ Op,
                                                const float* __restrict__ sums,
                                                float* __restrict__ out) {
  const long n4 = (long)NB * SQN * DM / 4;
  long i = (long)blockIdx.x * 256 + threadIdx.x;
  if (i >= n4) return;
  long e = i * 4;
  int b = (int)(e / ((long)SQN * DM));
  long rem = e - (long)b * SQN * DM;
  int row = (int)(rem / DM);
  const long z4 = (long)SQN * DM / 4;
  long i0 = (long)(b * NSPLIT) * z4 + (rem >> 2);
  float4 a0 = ((const float4*)Op)[i0];
  float4 a1 = ((const float4*)Op)[i0 + z4];
  float inv = 1.0f / sums[b * SQN + row];
  float4 r;
  r.x = (a0.x + a1.x) * inv;
  r.y = (a0.y + a1.y) * inv;
  r.z = (a0.z + a1.z) * inv;
  r.w = (a0.w + a1.w) * inv;
  ((float4*)out)[i] = r;
}

// ---------------- launch ----------------
extern "C" void kernel_launch(void* const* d_in, const int* in_sizes, int n_in,
                              void* d_out, int out_size, void* d_ws, size_t ws_size,
                              hipStream_t stream) {
  const float* hidden = (const float*)d_in[0];
  const float* ck = (const float*)d_in[1];
  const float* cv = (const float*)d_in[2];
  const float* Wq = (const float*)d_in[3];
  const float* bq = (const float*)d_in[4];
  const float* Wk = (const float*)d_in[5];
  const float* bk = (const float*)d_in[6];
  const float* Wv = (const float*)d_in[7];
  const float* bv = (const float*)d_in[8];
  (void)in_sizes; (void)n_in; (void)out_size; (void)ws_size;

  hipFuncSetAttribute(reinterpret_cast<const void*>(&k_gemm8<0>),
                      hipFuncAttributeMaxDynamicSharedMemorySize, 131072);
  hipFuncSetAttribute(reinterpret_cast<const void*>(&k_gemm8<1>),
                      hipFuncAttributeMaxDynamicSharedMemorySize, 131072);
  hipFuncSetAttribute(reinterpret_cast<const void*>(&k_gemm8<2>),
                      hipFuncAttributeMaxDynamicSharedMemorySize, 131072);

  char* base = (char*)d_ws;
  size_t off = 0;
  auto alloc = [&](size_t bytes) {
    char* p = base + off;
    off = (off + bytes + 255) & ~(size_t)255;
    return p;
  };
  // region0 (dead before PV): Hb, weights, Qb, Kb, Vtmp. Opart aliases it.
  u16* Hb = (u16*)alloc((size_t)NB * SQN * DM * 2);
  u16* Wall = (u16*)alloc((size_t)3 * DM * DM * 2);  // Wq|Wk|Wv stacked
  u16* Qb = (u16*)alloc((size_t)NB * SQN * DM * 2);
  u16* Kb = (u16*)alloc((size_t)NB * SKV * DM * 2);
  u16* Vtmp = (u16*)alloc((size_t)NB * SQN * DM * 2);
  float* Opart = (float*)base;  // [NB*NSPLIT][2048][1024] f32, aliases region0
  size_t opart_bytes = (size_t)NB * NSPLIT * SQN * DM * 4;
  if (off < opart_bytes) off = (opart_bytes + 255) & ~(size_t)255;
  u16* VT = (u16*)alloc((size_t)NB * DM * SKV * 2);
  u16* P = (u16*)alloc((size_t)NB * SQN * SKV * 2);
  float* sums = (float*)alloc((size_t)NB * SQN * 4);

  // fused prep: all conversions + sums zeroing in one dispatch
  k_prep<<<2048, 256, 0, stream>>>(hidden, Wq, Wk, Wv, ck, Hb, Wall, Kb, sums);

  // fused QKV projection: A=W-stack [3072][1024], B=H [8192][1024]
  k_gemm8<0><<<dim3(32, 12, 1), 512, 131072, stream>>>(
      Wall, Hb, Qb, Kb, Vtmp, nullptr, bq, bk, bv);

  // V^T
  k_build_vt<<<dim3(SKV / 64, DM / 64, NB), 256, 0, stream>>>(cv, Vtmp, VT);

  // S^T = K.Q^T with fused exp + row sums (batched over 4): A=K, B=Q
  k_gemm8<1><<<dim3(SQN / 256, SKV / 256, NB), 512, 131072, stream>>>(
      Kb, Qb, P, nullptr, nullptr, sums, nullptr, nullptr, nullptr);

  // PV split-K(2): A=P, B=VT
  k_gemm8<2><<<dim3(DM / 256, SQN / 256, NB * NSPLIT), 512, 131072, stream>>>(
      P, VT, Opart, nullptr, nullptr, nullptr, nullptr, nullptr, nullptr);

  // reduce partials + normalize
  k_reduce<<<(NB * SQN * DM / 4 + 255) / 256, 256, 0, stream>>>(
      Opart, sums, (float*)d_out);
}

// Round 17
// 424.230 us; speedup vs baseline: 1.2076x; 1.0088x over previous
//
#include <hip/hip_runtime.h>
#include <stdint.h>

// KVCacheAttention: B=4, Sq=2048, Scache=6144, Skv=8192, D=1024, scale=1/8.
// Round 17: round-16 VERBATIM except MODE1's grid mapping is transposed
// (bm=blockIdx.x over SKV, bn=blockIdx.y over SQN; launch (32,8,4)) so
// consecutive dispatch-order blocks share the 0.5MB Q-panel (L2-resident)
// and stream L3-resident K-panels. r13/r16 measured 270MB FETCH vs r12's
// 99MB with the panel-sharing orientation -- ~70us of HBM pressure in S.

#define DM 1024
#define NB 4
#define SQN 2048
#define SCC 6144
#define SKV 8192
#define NSPLIT 2
#define KSP (SKV / NSPLIT)

typedef unsigned short u16;
typedef __attribute__((ext_vector_type(8))) short short8;
typedef __attribute__((ext_vector_type(4))) float f32x4;

__device__ __forceinline__ u16 f2bf(float x) {
  unsigned u = __builtin_bit_cast(unsigned, x);
  u += 0x7fffu + ((u >> 16) & 1u);  // RNE; inputs finite
  return (u16)(u >> 16);
}

__device__ __forceinline__ ushort4 cv4(float4 v) {
  ushort4 u;
  u.x = f2bf(v.x); u.y = f2bf(v.y); u.z = f2bf(v.z); u.w = f2bf(v.w);
  return u;
}

__device__ __forceinline__ void gll16(const void* g, void* l) {
  __builtin_amdgcn_global_load_lds(
      (const __attribute__((address_space(1))) void*)g,
      (__attribute__((address_space(3))) void*)l, 16, 0, 0);
}

#define FENCE() asm volatile("" ::: "memory")
#define BARRIER()                      \
  do {                                 \
    FENCE();                           \
    __builtin_amdgcn_s_barrier();      \
    FENCE();                           \
  } while (0)

#define DSR(d, a, I) \
  asm volatile("ds_read_b128 %0, %1 offset:%2" : "=v"(d) : "v"(a), "i"(I))

#define VMC4() asm volatile("s_waitcnt vmcnt(4)" ::: "memory")
#define LGKM0()                                        \
  do {                                                 \
    asm volatile("s_waitcnt lgkmcnt(0)" ::: "memory"); \
    __builtin_amdgcn_sched_barrier(0);                 \
  } while (0)

// ---------------- fused prep: conversions + sums zero ----------------
__global__ __launch_bounds__(256) void k_prep(
    const float* __restrict__ hidden, const float* __restrict__ Wq,
    const float* __restrict__ Wk, const float* __restrict__ Wv,
    const float* __restrict__ ck, u16* __restrict__ Hb,
    u16* __restrict__ Wall, u16* __restrict__ Kb, float* __restrict__ sums) {
  const long NH = (long)NB * SQN * DM / 4;
  const long NW = (long)DM * DM / 4;
  const long NC = (long)NB * SCC * DM / 4;
  const long T1 = NH + 3 * NW;
  const long T2 = T1 + NC;
  const long T3 = T2 + (long)NB * SQN / 4;
  long i = (long)blockIdx.x * 256 + threadIdx.x;
  const long st = (long)gridDim.x * 256;
  for (; i < T3; i += st) {
    if (i < NH) {
      ((ushort4*)Hb)[i] = cv4(((const float4*)hidden)[i]);
    } else if (i < T1) {
      long r = i - NH;
      int w = (int)(r / NW);
      long o = r - (long)w * NW;
      const float* src = w == 0 ? Wq : (w == 1 ? Wk : Wv);
      ((ushort4*)Wall)[r] = cv4(((const float4*)src)[o]);
    } else if (i < T2) {
      long r = i - T1;
      float4 v = ((const float4*)ck)[r];
      long e = r * 4;
      int b = (int)(e / ((long)SCC * DM));
      long rem = e - (long)b * SCC * DM;
      *(ushort4*)(Kb + (long)b * SKV * DM + rem) = cv4(v);
    } else {
      float4 z;
      z.x = 0.f; z.y = 0.f; z.z = 0.f; z.w = 0.f;
      ((float4*)sums)[i - T2] = z;
    }
  }
}

// ---------------- V^T builder ----------------
__global__ __launch_bounds__(256) void k_build_vt(const float* __restrict__ cv,
                                                  const u16* __restrict__ vtmp,
                                                  u16* __restrict__ VT) {
  __shared__ u16 t[64][65];
  const int kv0 = blockIdx.x * 64;
  const int d0 = blockIdx.y * 64;
  const int b = blockIdx.z;
  const int c = threadIdx.x & 63;
  const int r4 = threadIdx.x >> 6;
#pragma unroll
  for (int p = 0; p < 16; ++p) {
    int kr = p * 4 + r4;
    int kv = kv0 + kr;
    int d = d0 + c;
    u16 u;
    if (kv < SCC)
      u = f2bf(cv[((long)b * SCC + kv) * DM + d]);
    else
      u = vtmp[((long)b * SQN + (kv - SCC)) * DM + d];
    t[kr][c] = u;
  }
  __syncthreads();
#pragma unroll
  for (int p = 0; p < 16; ++p) {
    int dr = p * 4 + r4;
    VT[((long)b * DM + d0 + dr) * SKV + kv0 + c] = t[c][dr];
  }
}

// ---------------- 256x256xBK64 quadrant-phase NT GEMM (r13) ----------------
// 512 thr = 8 waves (2M x 4N); per-wave out 128x64.
// LDS 128 KiB: A[2buf][2half][128r][64k] @0, B same @65536.
// 16B slot ^= row&7 via pre-swizzled source; linear gll16 dests.
// MODE1 grid is transposed: bm=x (SKV), bn=y (SQN) for L2 Q-panel sharing.
template <int MODE>
__global__ __launch_bounds__(512, 2) void k_gemm8(
    const u16* __restrict__ A, const u16* __restrict__ B0,
    void* __restrict__ C0, void* __restrict__ C1, void* __restrict__ C2,
    float* __restrict__ sums, const float* __restrict__ bias0,
    const float* __restrict__ bias1, const float* __restrict__ bias2) {
  extern __shared__ char smem[];
  const int tid = threadIdx.x;
  const int lane = tid & 63;
  const int wv = tid >> 6;   // 0..7
  const int wr = wv >> 2;    // 0..1
  const int wc = wv & 3;     // 0..3
  const int bm = (MODE == 1 ? blockIdx.x : blockIdx.y) * 256;  // A rows
  const int bn = (MODE == 1 ? blockIdx.y : blockIdx.x) * 256;  // B rows
  const int z = blockIdx.z;

  constexpr int LD = (MODE == 2) ? SKV : DM;
  constexpr int NT = ((MODE == 2) ? KSP : DM) / 64;

  const u16 *Ab_, *Bb_;
  if constexpr (MODE == 0) {
    Ab_ = A + (long)bm * LD;          // W-stack rows: out-d
    Bb_ = B0 + (long)bn * LD;         // H tokens
  } else if constexpr (MODE == 1) {
    Ab_ = A + ((long)z * SKV + bm) * LD;   // K rows: kv
    Bb_ = B0 + ((long)z * SQN + bn) * LD;  // Q rows: q
  } else {
    const int bb_ = z / NSPLIT, sp = z % NSPLIT;
    Ab_ = A + ((long)bb_ * SQN + bm) * (long)SKV + (long)sp * KSP;
    Bb_ = B0 + ((long)bb_ * DM + bn) * (long)SKV + (long)sp * KSP;
  }

  // ---- staging addresses (per-lane global, linear LDS dest) ----
  const int sg = tid >> 3;                     // 0..63
  const int ssl = ((tid & 7) ^ (sg & 7)) * 8;  // pre-swizzled col (elems)
  const u16* gA[2][2];  // [mh][g]: grow = g*128 + mh*64 + sg
  const u16* gB[2][2];  // [nh][g]: grow = (g*2 + (sg>>5))*64 + nh*32 + (sg&31)
#pragma unroll
  for (int mh = 0; mh < 2; ++mh)
#pragma unroll
    for (int g = 0; g < 2; ++g) {
      gA[mh][g] = Ab_ + (long)(g * 128 + mh * 64 + sg) * LD + ssl;
      gB[mh][g] = Bb_ + (long)((g * 2 + (sg >> 5)) * 64 + mh * 32 + (sg & 31)) * LD + ssl;
    }
  u16* lA = (u16*)smem + tid * 8;           // + bufN*16384 + mh*8192 + g*4096
  u16* lB = (u16*)smem + 32768 + tid * 8;

#define SA(MH, BUFN, KO)                                              \
  do {                                                                \
    gll16(gA[MH][0] + (KO), lA + (BUFN)*16384 + (MH)*8192);           \
    gll16(gA[MH][1] + (KO), lA + (BUFN)*16384 + (MH)*8192 + 4096);    \
  } while (0)
#define SB(NH, BUFN, KO)                                              \
  do {                                                                \
    gll16(gB[NH][0] + (KO), lB + (BUFN)*16384 + (NH)*8192);           \
    gll16(gB[NH][1] + (KO), lB + (BUFN)*16384 + (NH)*8192 + 4096);    \
  } while (0)

  // prologue: stage tile 0 halves A0,B0,B1,A1; VMC4 -> A0,B0 certified
  SA(0, 0, 0);
  SB(0, 0, 0);
  SB(1, 0, 0);
  SA(1, 0, 0);
  VMC4();
  BARRIER();

  f32x4 acc[8][4];
#pragma unroll
  for (int m = 0; m < 8; ++m)
#pragma unroll
    for (int n = 0; n < 4; ++n)
#pragma unroll
      for (int j = 0; j < 4; ++j) acc[m][n][j] = 0.0f;

  const int alane = lane & 15;
  const int sw = lane & 7;
  const int s0 = lane >> 4;
  const int slot0 = ((s0 ^ sw) * 16);
  const int slot1 = (((s0 + 4) ^ sw) * 16);
  const int aBase = (wr * 64 + alane) * 128;  // + imm mh*16384 + ms*2048
  const int bBase = (wc * 32 + alane) * 128;  // + imm nh*16384 + ns*2048

  short8 aF[4][2];     // [ms][kk], current mh
  short8 bF[2][2][2];  // [nh][ns][kk], both halves live

#define ARD8(MH, AR0, AR1)                           \
  _Pragma("unroll") for (int ms = 0; ms < 4; ++ms) { \
    DSR(aF[ms][0], AR0, (MH)*16384 + ms * 2048);     \
    DSR(aF[ms][1], AR1, (MH)*16384 + ms * 2048);     \
  }
#define BRD4(NH, BR0, BR1)                           \
  _Pragma("unroll") for (int ns = 0; ns < 2; ++ns) { \
    DSR(bF[NH][ns][0], BR0, (NH)*16384 + ns * 2048); \
    DSR(bF[NH][ns][1], BR1, (NH)*16384 + ns * 2048); \
  }
#define MFMA_Q(MH, NH)                                                     \
  do {                                                                     \
    __builtin_amdgcn_s_setprio(1);                                         \
    _Pragma("unroll") for (int ms = 0; ms < 4; ++ms)                       \
    _Pragma("unroll") for (int ns = 0; ns < 2; ++ns)                       \
    _Pragma("unroll") for (int kk = 0; kk < 2; ++kk)                       \
        acc[(MH)*4 + ms][(NH)*2 + ns] =                                    \
            __builtin_amdgcn_mfma_f32_16x16x32_bf16(                       \
                aF[ms][kk], bF[NH][ns][kk], acc[(MH)*4 + ms][(NH)*2 + ns], \
                0, 0, 0);                                                  \
    __builtin_amdgcn_s_setprio(0);                                         \
    __builtin_amdgcn_sched_barrier(0);                                     \
  } while (0)

// One K-tile: 4 quadrant phases, all reads pre-barrier, lgkm(0) post-barrier.
#define TILE_BODY(BUF, KT)                                            \
  do {                                                                \
    const long ko = (long)(((KT) + 1 < NT) ? (KT) + 1 : (KT)) * 64;   \
    const int aR0 = (BUF)*32768 + aBase + slot0;                      \
    const int aR1 = (BUF)*32768 + aBase + slot1;                      \
    const int bR0 = 65536 + (BUF)*32768 + bBase + slot0;              \
    const int bR1 = 65536 + (BUF)*32768 + bBase + slot1;              \
    /* p0: Q(mh0,nh0) */                                              \
    ARD8(0, aR0, aR1);                                                \
    BRD4(0, bR0, bR1);                                                \
    SA(0, (BUF) ^ 1, ko);                                             \
    VMC4();                                                           \
    BARRIER();                                                        \
    LGKM0();                                                          \
    MFMA_Q(0, 0);                                                     \
    /* p1: Q(mh0,nh1) */                                              \
    BRD4(1, bR0, bR1);                                                \
    SB(0, (BUF) ^ 1, ko);                                             \
    VMC4();                                                           \
    BARRIER();                                                        \
    LGKM0();                                                          \
    MFMA_Q(0, 1);                                                     \
    /* p2: Q(mh1,nh1) */                                              \
    ARD8(1, aR0, aR1);                                                \
    SB(1, (BUF) ^ 1, ko);                                             \
    BARRIER();                                                        \
    LGKM0();                                                          \
    MFMA_Q(1, 1);                                                     \
    /* p3: Q(mh1,nh0) (all frags held) */                             \
    SA(1, (BUF) ^ 1, ko);                                             \
    VMC4();                                                           \
    BARRIER();                                                        \
    MFMA_Q(1, 0);                                                     \
  } while (0)

  for (int t2 = 0; t2 < NT; t2 += 2) {
    TILE_BODY(0, t2);
    TILE_BODY(1, t2 + 1);
  }
#undef TILE_BODY
#undef ARD8
#undef BRD4
#undef MFMA_Q
#undef SA
#undef SB

  // ---------------- epilogue (r13 verbatim) ----------------
  const int rsub = (lane >> 4) * 4;

  if constexpr (MODE == 0) {
    // A=W-stack: acc row = out-d, col = token. which = bm>>10 per block.
    const int which = bm >> 10;
    const float* bp = which == 0 ? bias0 : (which == 1 ? bias1 : bias2);
    u16* Cq = (u16*)C0;
    u16* Ck = (u16*)C1;
    u16* Cv = (u16*)C2;
    const int od_base = (bm & 1023) + wr * 128 + rsub;
#pragma unroll
    for (int n = 0; n < 4; ++n) {
      int token = bn + wc * 64 + n * 16 + alane;
      u16* dst;
      if (which == 1) {
        int b = token >> 11, ss = token & 2047;
        dst = Ck + ((long)b * SKV + SCC + ss) * DM;
      } else if (which == 0) {
        dst = Cq + (long)token * DM;
      } else {
        dst = Cv + (long)token * DM;
      }
#pragma unroll
      for (int m = 0; m < 8; ++m) {
        int cc = od_base + m * 16;
        float4 bb = *(const float4*)(bp + cc);
        ushort4 u;
        u.x = f2bf(acc[m][n][0] + bb.x);
        u.y = f2bf(acc[m][n][1] + bb.y);
        u.z = f2bf(acc[m][n][2] + bb.z);
        u.w = f2bf(acc[m][n][3] + bb.w);
        *(ushort4*)(dst + cc) = u;
      }
    }
  } else if constexpr (MODE == 1) {
    // A=K: acc row = kv, col = q. store P[q][kv] ushort4; rowsum per q.
    u16* Pp = (u16*)C0 + (long)z * SQN * SKV;
    float* sb = sums + z * SQN;
    const float CE = 0.18033688011112042f;  // log2(e)/8
    const int kv_base = bm + wr * 128 + rsub;
#pragma unroll
    for (int n = 0; n < 4; ++n) {
      int q = bn + wc * 64 + n * 16 + alane;
      u16* prow = Pp + (long)q * SKV;
      float part = 0.f;
#pragma unroll
      for (int m = 0; m < 8; ++m) {
        int kv = kv_base + m * 16;
        float e0 = exp2f(acc[m][n][0] * CE);
        float e1 = exp2f(acc[m][n][1] * CE);
        float e2 = exp2f(acc[m][n][2] * CE);
        float e3 = exp2f(acc[m][n][3] * CE);
        part += (e0 + e1) + (e2 + e3);
        ushort4 u;
        u.x = f2bf(e0); u.y = f2bf(e1); u.z = f2bf(e2); u.w = f2bf(e3);
        *(ushort4*)(prow + kv) = u;
      }
      part += __shfl_xor(part, 16);
      part += __shfl_xor(part, 32);
      if ((lane >> 4) == 0) atomicAdd(&sb[q], part);
    }
  } else {
    // acc row = q, col = d. f32 stores, 64B sectors.
    float* Cp = (float*)C0 + (long)z * SQN * DM;
#pragma unroll
    for (int n = 0; n < 4; ++n) {
      int col = bn + wc * 64 + n * 16 + alane;
#pragma unroll
      for (int m = 0; m < 8; ++m)
#pragma unroll
        for (int j = 0; j < 4; ++j) {
          int row = bm + wr * 128 + m * 16 + rsub + j;
          Cp[(long)row * DM + col] = acc[m][n][j];
        }
    }
  }
}

// ---------------- reduce split-K partials + normalize ----------------
__global__ __launch_bounds__(256) void k_reduce(const float* __restrict__ Op,
                                                const float* __restrict__ sums,
                                                float* __restrict__ out) {
  const long n4 = (long)NB * SQN * DM / 4;
  long i = (long)blockIdx.x * 256 + threadIdx.x;
  if (i >= n4) return;
  long e = i * 4;
  int b = (int)(e / ((long)SQN * DM));
  long rem = e - (long)b * SQN * DM;
  int row = (int)(rem / DM);
  const long z4 = (long)SQN * DM / 4;
  long i0 = (long)(b * NSPLIT) * z4 + (rem >> 2);
  float4 a0 = ((const float4*)Op)[i0];
  float4 a1 = ((const float4*)Op)[i0 + z4];
  float inv = 1.0f / sums[b * SQN + row];
  float4 r;
  r.x = (a0.x + a1.x) * inv;
  r.y = (a0.y + a1.y) * inv;
  r.z = (a0.z + a1.z) * inv;
  r.w = (a0.w + a1.w) * inv;
  ((float4*)out)[i] = r;
}

// ---------------- launch ----------------
extern "C" void kernel_launch(void* const* d_in, const int* in_sizes, int n_in,
                              void* d_out, int out_size, void* d_ws, size_t ws_size,
                              hipStream_t stream) {
  const float* hidden = (const float*)d_in[0];
  const float* ck = (const float*)d_in[1];
  const float* cv = (const float*)d_in[2];
  const float* Wq = (const float*)d_in[3];
  const float* bq = (const float*)d_in[4];
  const float* Wk = (const float*)d_in[5];
  const float* bk = (const float*)d_in[6];
  const float* Wv = (const float*)d_in[7];
  const float* bv = (const float*)d_in[8];
  (void)in_sizes; (void)n_in; (void)out_size; (void)ws_size;

  hipFuncSetAttribute(reinterpret_cast<const void*>(&k_gemm8<0>),
                      hipFuncAttributeMaxDynamicSharedMemorySize, 131072);
  hipFuncSetAttribute(reinterpret_cast<const void*>(&k_gemm8<1>),
                      hipFuncAttributeMaxDynamicSharedMemorySize, 131072);
  hipFuncSetAttribute(reinterpret_cast<const void*>(&k_gemm8<2>),
                      hipFuncAttributeMaxDynamicSharedMemorySize, 131072);

  char* base = (char*)d_ws;
  size_t off = 0;
  auto alloc = [&](size_t bytes) {
    char* p = base + off;
    off = (off + bytes + 255) & ~(size_t)255;
    return p;
  };
  // region0 (dead before PV): Hb, weights, Qb, Kb, Vtmp. Opart aliases it.
  u16* Hb = (u16*)alloc((size_t)NB * SQN * DM * 2);
  u16* Wall = (u16*)alloc((size_t)3 * DM * DM * 2);  // Wq|Wk|Wv stacked
  u16* Qb = (u16*)alloc((size_t)NB * SQN * DM * 2);
  u16* Kb = (u16*)alloc((size_t)NB * SKV * DM * 2);
  u16* Vtmp = (u16*)alloc((size_t)NB * SQN * DM * 2);
  float* Opart = (float*)base;  // [NB*NSPLIT][2048][1024] f32, aliases region0
  size_t opart_bytes = (size_t)NB * NSPLIT * SQN * DM * 4;
  if (off < opart_bytes) off = (opart_bytes + 255) & ~(size_t)255;
  u16* VT = (u16*)alloc((size_t)NB * DM * SKV * 2);
  u16* P = (u16*)alloc((size_t)NB * SQN * SKV * 2);
  float* sums = (float*)alloc((size_t)NB * SQN * 4);

  // fused prep: all conversions + sums zeroing in one dispatch
  k_prep<<<2048, 256, 0, stream>>>(hidden, Wq, Wk, Wv, ck, Hb, Wall, Kb, sums);

  // fused QKV projection: A=W-stack [3072][1024], B=H [8192][1024]
  k_gemm8<0><<<dim3(32, 12, 1), 512, 131072, stream>>>(
      Wall, Hb, Qb, Kb, Vtmp, nullptr, bq, bk, bv);

  // V^T
  k_build_vt<<<dim3(SKV / 64, DM / 64, NB), 256, 0, stream>>>(cv, Vtmp, VT);

  // S^T = K.Q^T, transposed grid: x walks K-panels, y holds Q-panel
  k_gemm8<1><<<dim3(SKV / 256, SQN / 256, NB), 512, 131072, stream>>>(
      Kb, Qb, P, nullptr, nullptr, sums, nullptr, nullptr, nullptr);

  // PV split-K(2): A=P, B=VT
  k_gemm8<2><<<dim3(DM / 256, SQN / 256, NB * NSPLIT), 512, 131072, stream>>>(
      P, VT, Opart, nullptr, nullptr, nullptr, nullptr, nullptr, nullptr);

  // reduce partials + normalize
  k_reduce<<<(NB * SQN * DM / 4 + 255) / 256, 256, 0, stream>>>(
      Opart, sums, (float*)d_out);
}

// Round 18
// 403.654 us; speedup vs baseline: 1.2692x; 1.0510x over previous
//
#include <hip/hip_runtime.h>
#include <stdint.h>

// KVCacheAttention: B=4, Sq=2048, Scache=6144, Skv=8192, D=1024, scale=1/8.
// Round 18: round-17 VERBATIM except the V path: MODE0's accumulator is
// already in V^T orientation (row=out-d, col=token), so the QKV epilogue
// writes the new-V region of VT directly (16 lanes = 32B sector-full rows);
// Vtmp is deleted and build_vt shrinks to the cached region (96,16,4).

#define DM 1024
#define NB 4
#define SQN 2048
#define SCC 6144
#define SKV 8192
#define NSPLIT 2
#define KSP (SKV / NSPLIT)

typedef unsigned short u16;
typedef __attribute__((ext_vector_type(8))) short short8;
typedef __attribute__((ext_vector_type(4))) float f32x4;

__device__ __forceinline__ u16 f2bf(float x) {
  unsigned u = __builtin_bit_cast(unsigned, x);
  u += 0x7fffu + ((u >> 16) & 1u);  // RNE; inputs finite
  return (u16)(u >> 16);
}

__device__ __forceinline__ ushort4 cv4(float4 v) {
  ushort4 u;
  u.x = f2bf(v.x); u.y = f2bf(v.y); u.z = f2bf(v.z); u.w = f2bf(v.w);
  return u;
}

__device__ __forceinline__ void gll16(const void* g, void* l) {
  __builtin_amdgcn_global_load_lds(
      (const __attribute__((address_space(1))) void*)g,
      (__attribute__((address_space(3))) void*)l, 16, 0, 0);
}

#define FENCE() asm volatile("" ::: "memory")
#define BARRIER()                      \
  do {                                 \
    FENCE();                           \
    __builtin_amdgcn_s_barrier();      \
    FENCE();                           \
  } while (0)

#define DSR(d, a, I) \
  asm volatile("ds_read_b128 %0, %1 offset:%2" : "=v"(d) : "v"(a), "i"(I))

#define VMC4() asm volatile("s_waitcnt vmcnt(4)" ::: "memory")
#define LGKM0()                                        \
  do {                                                 \
    asm volatile("s_waitcnt lgkmcnt(0)" ::: "memory"); \
    __builtin_amdgcn_sched_barrier(0);                 \
  } while (0)

// ---------------- fused prep: conversions + sums zero ----------------
__global__ __launch_bounds__(256) void k_prep(
    const float* __restrict__ hidden, const float* __restrict__ Wq,
    const float* __restrict__ Wk, const float* __restrict__ Wv,
    const float* __restrict__ ck, u16* __restrict__ Hb,
    u16* __restrict__ Wall, u16* __restrict__ Kb, float* __restrict__ sums) {
  const long NH = (long)NB * SQN * DM / 4;
  const long NW = (long)DM * DM / 4;
  const long NC = (long)NB * SCC * DM / 4;
  const long T1 = NH + 3 * NW;
  const long T2 = T1 + NC;
  const long T3 = T2 + (long)NB * SQN / 4;
  long i = (long)blockIdx.x * 256 + threadIdx.x;
  const long st = (long)gridDim.x * 256;
  for (; i < T3; i += st) {
    if (i < NH) {
      ((ushort4*)Hb)[i] = cv4(((const float4*)hidden)[i]);
    } else if (i < T1) {
      long r = i - NH;
      int w = (int)(r / NW);
      long o = r - (long)w * NW;
      const float* src = w == 0 ? Wq : (w == 1 ? Wk : Wv);
      ((ushort4*)Wall)[r] = cv4(((const float4*)src)[o]);
    } else if (i < T2) {
      long r = i - T1;
      float4 v = ((const float4*)ck)[r];
      long e = r * 4;
      int b = (int)(e / ((long)SCC * DM));
      long rem = e - (long)b * SCC * DM;
      *(ushort4*)(Kb + (long)b * SKV * DM + rem) = cv4(v);
    } else {
      float4 z;
      z.x = 0.f; z.y = 0.f; z.z = 0.f; z.w = 0.f;
      ((float4*)sums)[i - T2] = z;
    }
  }
}

// ---------------- V^T builder (cached region only: kv < SCC) ----------------
__global__ __launch_bounds__(256) void k_build_vt(const float* __restrict__ cv,
                                                  u16* __restrict__ VT) {
  __shared__ u16 t[64][65];
  const int kv0 = blockIdx.x * 64;
  const int d0 = blockIdx.y * 64;
  const int b = blockIdx.z;
  const int c = threadIdx.x & 63;
  const int r4 = threadIdx.x >> 6;
#pragma unroll
  for (int p = 0; p < 16; ++p) {
    int kr = p * 4 + r4;
    t[kr][c] = f2bf(cv[((long)b * SCC + kv0 + kr) * DM + d0 + c]);
  }
  __syncthreads();
#pragma unroll
  for (int p = 0; p < 16; ++p) {
    int dr = p * 4 + r4;
    VT[((long)b * DM + d0 + dr) * SKV + kv0 + c] = t[c][dr];
  }
}

// ---------------- 256x256xBK64 quadrant-phase NT GEMM (r13) ----------------
// 512 thr = 8 waves (2M x 4N); per-wave out 128x64.
// LDS 128 KiB: A[2buf][2half][128r][64k] @0, B same @65536.
// 16B slot ^= row&7 via pre-swizzled source; linear gll16 dests.
// MODE1 grid transposed (bm=x over SKV) for L2 Q-panel sharing.
template <int MODE>
__global__ __launch_bounds__(512, 2) void k_gemm8(
    const u16* __restrict__ A, const u16* __restrict__ B0,
    void* __restrict__ C0, void* __restrict__ C1, void* __restrict__ C2,
    float* __restrict__ sums, const float* __restrict__ bias0,
    const float* __restrict__ bias1, const float* __restrict__ bias2) {
  extern __shared__ char smem[];
  const int tid = threadIdx.x;
  const int lane = tid & 63;
  const int wv = tid >> 6;   // 0..7
  const int wr = wv >> 2;    // 0..1
  const int wc = wv & 3;     // 0..3
  const int bm = (MODE == 1 ? blockIdx.x : blockIdx.y) * 256;  // A rows
  const int bn = (MODE == 1 ? blockIdx.y : blockIdx.x) * 256;  // B rows
  const int z = blockIdx.z;

  constexpr int LD = (MODE == 2) ? SKV : DM;
  constexpr int NT = ((MODE == 2) ? KSP : DM) / 64;

  const u16 *Ab_, *Bb_;
  if constexpr (MODE == 0) {
    Ab_ = A + (long)bm * LD;          // W-stack rows: out-d
    Bb_ = B0 + (long)bn * LD;         // H tokens
  } else if constexpr (MODE == 1) {
    Ab_ = A + ((long)z * SKV + bm) * LD;   // K rows: kv
    Bb_ = B0 + ((long)z * SQN + bn) * LD;  // Q rows: q
  } else {
    const int bb_ = z / NSPLIT, sp = z % NSPLIT;
    Ab_ = A + ((long)bb_ * SQN + bm) * (long)SKV + (long)sp * KSP;
    Bb_ = B0 + ((long)bb_ * DM + bn) * (long)SKV + (long)sp * KSP;
  }

  // ---- staging addresses (per-lane global, linear LDS dest) ----
  const int sg = tid >> 3;                     // 0..63
  const int ssl = ((tid & 7) ^ (sg & 7)) * 8;  // pre-swizzled col (elems)
  const u16* gA[2][2];  // [mh][g]: grow = g*128 + mh*64 + sg
  const u16* gB[2][2];  // [nh][g]: grow = (g*2 + (sg>>5))*64 + nh*32 + (sg&31)
#pragma unroll
  for (int mh = 0; mh < 2; ++mh)
#pragma unroll
    for (int g = 0; g < 2; ++g) {
      gA[mh][g] = Ab_ + (long)(g * 128 + mh * 64 + sg) * LD + ssl;
      gB[mh][g] = Bb_ + (long)((g * 2 + (sg >> 5)) * 64 + mh * 32 + (sg & 31)) * LD + ssl;
    }
  u16* lA = (u16*)smem + tid * 8;           // + bufN*16384 + mh*8192 + g*4096
  u16* lB = (u16*)smem + 32768 + tid * 8;

#define SA(MH, BUFN, KO)                                              \
  do {                                                                \
    gll16(gA[MH][0] + (KO), lA + (BUFN)*16384 + (MH)*8192);           \
    gll16(gA[MH][1] + (KO), lA + (BUFN)*16384 + (MH)*8192 + 4096);    \
  } while (0)
#define SB(NH, BUFN, KO)                                              \
  do {                                                                \
    gll16(gB[NH][0] + (KO), lB + (BUFN)*16384 + (NH)*8192);           \
    gll16(gB[NH][1] + (KO), lB + (BUFN)*16384 + (NH)*8192 + 4096);    \
  } while (0)

  // prologue: stage tile 0 halves A0,B0,B1,A1; VMC4 -> A0,B0 certified
  SA(0, 0, 0);
  SB(0, 0, 0);
  SB(1, 0, 0);
  SA(1, 0, 0);
  VMC4();
  BARRIER();

  f32x4 acc[8][4];
#pragma unroll
  for (int m = 0; m < 8; ++m)
#pragma unroll
    for (int n = 0; n < 4; ++n)
#pragma unroll
      for (int j = 0; j < 4; ++j) acc[m][n][j] = 0.0f;

  const int alane = lane & 15;
  const int sw = lane & 7;
  const int s0 = lane >> 4;
  const int slot0 = ((s0 ^ sw) * 16);
  const int slot1 = (((s0 + 4) ^ sw) * 16);
  const int aBase = (wr * 64 + alane) * 128;  // + imm mh*16384 + ms*2048
  const int bBase = (wc * 32 + alane) * 128;  // + imm nh*16384 + ns*2048

  short8 aF[4][2];     // [ms][kk], current mh
  short8 bF[2][2][2];  // [nh][ns][kk], both halves live

#define ARD8(MH, AR0, AR1)                           \
  _Pragma("unroll") for (int ms = 0; ms < 4; ++ms) { \
    DSR(aF[ms][0], AR0, (MH)*16384 + ms * 2048);     \
    DSR(aF[ms][1], AR1, (MH)*16384 + ms * 2048);     \
  }
#define BRD4(NH, BR0, BR1)                           \
  _Pragma("unroll") for (int ns = 0; ns < 2; ++ns) { \
    DSR(bF[NH][ns][0], BR0, (NH)*16384 + ns * 2048); \
    DSR(bF[NH][ns][1], BR1, (NH)*16384 + ns * 2048); \
  }
#define MFMA_Q(MH, NH)                                                     \
  do {                                                                     \
    __builtin_amdgcn_s_setprio(1);                                         \
    _Pragma("unroll") for (int ms = 0; ms < 4; ++ms)                       \
    _Pragma("unroll") for (int ns = 0; ns < 2; ++ns)                       \
    _Pragma("unroll") for (int kk = 0; kk < 2; ++kk)                       \
        acc[(MH)*4 + ms][(NH)*2 + ns] =                                    \
            __builtin_amdgcn_mfma_f32_16x16x32_bf16(                       \
                aF[ms][kk], bF[NH][ns][kk], acc[(MH)*4 + ms][(NH)*2 + ns], \
                0, 0, 0);                                                  \
    __builtin_amdgcn_s_setprio(0);                                         \
    __builtin_amdgcn_sched_barrier(0);                                     \
  } while (0)

// One K-tile: 4 quadrant phases, all reads pre-barrier, lgkm(0) post-barrier.
#define TILE_BODY(BUF, KT)                                            \
  do {                                                                \
    const long ko = (long)(((KT) + 1 < NT) ? (KT) + 1 : (KT)) * 64;   \
    const int aR0 = (BUF)*32768 + aBase + slot0;                      \
    const int aR1 = (BUF)*32768 + aBase + slot1;                      \
    const int bR0 = 65536 + (BUF)*32768 + bBase + slot0;              \
    const int bR1 = 65536 + (BUF)*32768 + bBase + slot1;              \
    /* p0: Q(mh0,nh0) */                                              \
    ARD8(0, aR0, aR1);                                                \
    BRD4(0, bR0, bR1);                                                \
    SA(0, (BUF) ^ 1, ko);                                             \
    VMC4();                                                           \
    BARRIER();                                                        \
    LGKM0();                                                          \
    MFMA_Q(0, 0);                                                     \
    /* p1: Q(mh0,nh1) */                                              \
    BRD4(1, bR0, bR1);                                                \
    SB(0, (BUF) ^ 1, ko);                                             \
    VMC4();                                                           \
    BARRIER();                                                        \
    LGKM0();                                                          \
    MFMA_Q(0, 1);                                                     \
    /* p2: Q(mh1,nh1) */                                              \
    ARD8(1, aR0, aR1);                                                \
    SB(1, (BUF) ^ 1, ko);                                             \
    BARRIER();                                                        \
    LGKM0();                                                          \
    MFMA_Q(1, 1);                                                     \
    /* p3: Q(mh1,nh0) (all frags held) */                             \
    SA(1, (BUF) ^ 1, ko);                                             \
    VMC4();                                                           \
    BARRIER();                                                        \
    MFMA_Q(1, 0);                                                     \
  } while (0)

  for (int t2 = 0; t2 < NT; t2 += 2) {
    TILE_BODY(0, t2);
    TILE_BODY(1, t2 + 1);
  }
#undef TILE_BODY
#undef ARD8
#undef BRD4
#undef MFMA_Q
#undef SA
#undef SB

  // ---------------- epilogue ----------------
  const int rsub = (lane >> 4) * 4;

  if constexpr (MODE == 0) {
    // A=W-stack: acc row = out-d, col = token. which = bm>>10 per block.
    const int which = bm >> 10;
    const float* bp = which == 0 ? bias0 : (which == 1 ? bias1 : bias2);
    u16* Cq = (u16*)C0;
    u16* Ck = (u16*)C1;
    u16* Cvt = (u16*)C2;  // VT base [b][d][kv]
    const int od_base = (bm & 1023) + wr * 128 + rsub;
    if (which == 2) {
      // V: acc is already V^T -- write VT[b][d][SCC+s] directly.
      // 16 lanes (alane) span 16 consecutive tokens -> 32B sector-full rows.
#pragma unroll
      for (int n = 0; n < 4; ++n) {
        int token = bn + wc * 64 + n * 16 + alane;
        int b = token >> 11, ss = token & 2047;
        u16* vtb = Cvt + (long)b * DM * SKV + SCC + ss;
#pragma unroll
        for (int m = 0; m < 8; ++m) {
          int cc = od_base + m * 16;
          float4 bb = *(const float4*)(bp + cc);
          float bv4[4] = {bb.x, bb.y, bb.z, bb.w};
#pragma unroll
          for (int jj = 0; jj < 4; ++jj)
            vtb[(long)(cc + jj) * SKV] = f2bf(acc[m][n][jj] + bv4[jj]);
        }
      }
    } else {
#pragma unroll
      for (int n = 0; n < 4; ++n) {
        int token = bn + wc * 64 + n * 16 + alane;
        u16* dst;
        if (which == 1) {
          int b = token >> 11, ss = token & 2047;
          dst = Ck + ((long)b * SKV + SCC + ss) * DM;
        } else {
          dst = Cq + (long)token * DM;
        }
#pragma unroll
        for (int m = 0; m < 8; ++m) {
          int cc = od_base + m * 16;
          float4 bb = *(const float4*)(bp + cc);
          ushort4 u;
          u.x = f2bf(acc[m][n][0] + bb.x);
          u.y = f2bf(acc[m][n][1] + bb.y);
          u.z = f2bf(acc[m][n][2] + bb.z);
          u.w = f2bf(acc[m][n][3] + bb.w);
          *(ushort4*)(dst + cc) = u;
        }
      }
    }
  } else if constexpr (MODE == 1) {
    // A=K: acc row = kv, col = q. store P[q][kv] ushort4; rowsum per q.
    u16* Pp = (u16*)C0 + (long)z * SQN * SKV;
    float* sb = sums + z * SQN;
    const float CE = 0.18033688011112042f;  // log2(e)/8
    const int kv_base = bm + wr * 128 + rsub;
#pragma unroll
    for (int n = 0; n < 4; ++n) {
      int q = bn + wc * 64 + n * 16 + alane;
      u16* prow = Pp + (long)q * SKV;
      float part = 0.f;
#pragma unroll
      for (int m = 0; m < 8; ++m) {
        int kv = kv_base + m * 16;
        float e0 = exp2f(acc[m][n][0] * CE);
        float e1 = exp2f(acc[m][n][1] * CE);
        float e2 = exp2f(acc[m][n][2] * CE);
        float e3 = exp2f(acc[m][n][3] * CE);
        part += (e0 + e1) + (e2 + e3);
        ushort4 u;
        u.x = f2bf(e0); u.y = f2bf(e1); u.z = f2bf(e2); u.w = f2bf(e3);
        *(ushort4*)(prow + kv) = u;
      }
      part += __shfl_xor(part, 16);
      part += __shfl_xor(part, 32);
      if ((lane >> 4) == 0) atomicAdd(&sb[q], part);
    }
  } else {
    // acc row = q, col = d. f32 stores, 64B sectors.
    float* Cp = (float*)C0 + (long)z * SQN * DM;
#pragma unroll
    for (int n = 0; n < 4; ++n) {
      int col = bn + wc * 64 + n * 16 + alane;
#pragma unroll
      for (int m = 0; m < 8; ++m)
#pragma unroll
        for (int j = 0; j < 4; ++j) {
          int row = bm + wr * 128 + m * 16 + rsub + j;
          Cp[(long)row * DM + col] = acc[m][n][j];
        }
    }
  }
}

// ---------------- reduce split-K partials + normalize ----------------
__global__ __launch_bounds__(256) void k_reduce(const float* __restrict__ Op,
                                                const float* __restrict__ sums,
                                                float* __restrict__ out) {
  const long n4 = (long)NB * SQN * DM / 4;
  long i = (long)blockIdx.x * 256 + threadIdx.x;
  if (i >= n4) return;
  long e = i * 4;
  int b = (int)(e / ((long)SQN * DM));
  long rem = e - (long)b * SQN * DM;
  int row = (int)(rem / DM);
  const long z4 = (long)SQN * DM / 4;
  long i0 = (long)(b * NSPLIT) * z4 + (rem >> 2);
  float4 a0 = ((const float4*)Op)[i0];
  float4 a1 = ((const float4*)Op)[i0 + z4];
  float inv = 1.0f / sums[b * SQN + row];
  float4 r;
  r.x = (a0.x + a1.x) * inv;
  r.y = (a0.y + a1.y) * inv;
  r.z = (a0.z + a1.z) * inv;
  r.w = (a0.w + a1.w) * inv;
  ((float4*)out)[i] = r;
}

// ---------------- launch ----------------
extern "C" void kernel_launch(void* const* d_in, const int* in_sizes, int n_in,
                              void* d_out, int out_size, void* d_ws, size_t ws_size,
                              hipStream_t stream) {
  const float* hidden = (const float*)d_in[0];
  const float* ck = (const float*)d_in[1];
  const float* cv = (const float*)d_in[2];
  const float* Wq = (const float*)d_in[3];
  const float* bq = (const float*)d_in[4];
  const float* Wk = (const float*)d_in[5];
  const float* bk = (const float*)d_in[6];
  const float* Wv = (const float*)d_in[7];
  const float* bv = (const float*)d_in[8];
  (void)in_sizes; (void)n_in; (void)out_size; (void)ws_size;

  hipFuncSetAttribute(reinterpret_cast<const void*>(&k_gemm8<0>),
                      hipFuncAttributeMaxDynamicSharedMemorySize, 131072);
  hipFuncSetAttribute(reinterpret_cast<const void*>(&k_gemm8<1>),
                      hipFuncAttributeMaxDynamicSharedMemorySize, 131072);
  hipFuncSetAttribute(reinterpret_cast<const void*>(&k_gemm8<2>),
                      hipFuncAttributeMaxDynamicSharedMemorySize, 131072);

  char* base = (char*)d_ws;
  size_t off = 0;
  auto alloc = [&](size_t bytes) {
    char* p = base + off;
    off = (off + bytes + 255) & ~(size_t)255;
    return p;
  };
  // region0 (dead before PV): Hb, weights, Qb, Kb. Opart aliases it.
  u16* Hb = (u16*)alloc((size_t)NB * SQN * DM * 2);
  u16* Wall = (u16*)alloc((size_t)3 * DM * DM * 2);  // Wq|Wk|Wv stacked
  u16* Qb = (u16*)alloc((size_t)NB * SQN * DM * 2);
  u16* Kb = (u16*)alloc((size_t)NB * SKV * DM * 2);
  float* Opart = (float*)base;  // [NB*NSPLIT][2048][1024] f32, aliases region0
  size_t opart_bytes = (size_t)NB * NSPLIT * SQN * DM * 4;
  if (off < opart_bytes) off = (opart_bytes + 255) & ~(size_t)255;
  u16* VT = (u16*)alloc((size_t)NB * DM * SKV * 2);
  u16* P = (u16*)alloc((size_t)NB * SQN * SKV * 2);
  float* sums = (float*)alloc((size_t)NB * SQN * 4);

  // fused prep: all conversions + sums zeroing in one dispatch
  k_prep<<<2048, 256, 0, stream>>>(hidden, Wq, Wk, Wv, ck, Hb, Wall, Kb, sums);

  // fused QKV projection: A=W-stack [3072][1024], B=H [8192][1024];
  // V third writes VT[.., SCC..SKV) directly.
  k_gemm8<0><<<dim3(32, 12, 1), 512, 131072, stream>>>(
      Wall, Hb, Qb, Kb, VT, nullptr, bq, bk, bv);

  // V^T cached region (kv < SCC)
  k_build_vt<<<dim3(SCC / 64, DM / 64, NB), 256, 0, stream>>>(cv, VT);

  // S^T = K.Q^T, transposed grid: x walks K-panels, y holds Q-panel
  k_gemm8<1><<<dim3(SKV / 256, SQN / 256, NB), 512, 131072, stream>>>(
      Kb, Qb, P, nullptr, nullptr, sums, nullptr, nullptr, nullptr);

  // PV split-K(2): A=P, B=VT
  k_gemm8<2><<<dim3(DM / 256, SQN / 256, NB * NSPLIT), 512, 131072, stream>>>(
      P, VT, Opart, nullptr, nullptr, nullptr, nullptr, nullptr, nullptr);

  // reduce partials + normalize
  k_reduce<<<(NB * SQN * DM / 4 + 255) / 256, 256, 0, stream>>>(
      Opart, sums, (float*)d_out);
}